// Round 3
// baseline (808.175 us; speedup 1.0000x reference)
//
#include <hip/hip_runtime.h>

// ROIAlign3d: input [2,1024,32,16,16] f32, rois [32,5] f32 -> out [32,1024,32,7,7] f32
//
// Round-3 design — conflict-free-by-construction LDS:
//  - layout [cell 256][plane 64] (CS=68 floats incl. 4 pad). Tap read: 16-lane
//    group reads one cell's 64 planes = contiguous 256B (proven-good b128
//    pattern); data-INDEPENDENT uniform 8x/bank per wave instr.
//  - staging transpose lane-mapped so ds_write_b128 bank-group
//    (4(l&1) + (l>>4) + j) covers all 8 groups uniformly -> conflict-free.
//  - merged 3x3 stencil (valid since roi w,h <= 144px = 9 cells -> bin <= 9/7,
//    samples <1 cell apart) + clamp-shift (base<=13, zero weights shift out)
//    so reads never exceed index 15: no margins, no zero-fill.
//  - work unit: 16-lane group = (roi, ph, pw-quad{0-3 or 3-6}) x 64 planes;
//    per lane 4 planes x 4 bins -> 4 contiguous dword stores per plane.
//    pw3 written twice with identical value (L2 dedupes; HBM writes ~205MB).
//  - 512 thr, ~77KB LDS -> 2 blocks/CU = 16 waves/CU.

constexpr int kPH = 7, kPW = 7;
constexpr float kSCALE = 0.0625f;
constexpr int kNC = 1024, kNL = 32;
constexpr int kCL = kNC * kNL;            // 32768 planes per batch
constexpr int kNROI = 32;
constexpr int kPPB = 64;                  // planes per block
constexpr int kTPB = 512;
constexpr int kCS = 68;                   // floats per cell column (64 planes + 4 pad)
constexpr int kRS = 16 * kCS;             // 1088 floats per y-row
constexpr int kSPN = 256 * kCS;           // 17408 floats = 69632 B
constexpr int kNT = kNROI * kPH;          // 224 table entries per axis

__global__ __launch_bounds__(kTPB, 4) void roialign3d_kernel(
    const float* __restrict__ input, const float* __restrict__ rois,
    float* __restrict__ out)
{
    __shared__ __align__(16) float sp[kSPN];
    __shared__ __align__(16) float4 syt[kNT];   // w0,w1,w2, bitcast(ybase*kRS)
    __shared__ __align__(16) float4 sxt[kNT];   // w0,w1,w2, bitcast(xbase*kCS)
    __shared__ int slist[kNROI];
    __shared__ int snroi;

    const int b   = blockIdx.x & 1;
    const int cl0 = (blockIdx.x >> 1) * kPPB;
    const int tid = threadIdx.x;
    const int l   = tid & 63;
    const int wv  = tid >> 6;                 // wave 0..7

    // ---------------- stage 64 planes of batch b -> [cell][plane] ----------------
    {
        const int ql  = l & 15;
        const int ph4 = l >> 4;
        #pragma unroll
        for (int t = 0; t < 2; ++t) {
            const int q   = ql + 16 * (wv & 3);            // cell-quad 0..63
            const int pg4 = ph4 + 4 * (wv >> 2) + 8 * t;   // plane-group 0..15
            const float4* src = reinterpret_cast<const float4*>(
                input + (size_t)(b * kCL + cl0 + pg4 * 4) * 256) + q;
            const float4 v0 = src[0];
            const float4 v1 = src[64];
            const float4 v2 = src[128];
            const float4 v3 = src[192];
            float* dst = sp + (q * 4) * kCS + pg4 * 4;
            *reinterpret_cast<float4*>(dst + 0 * kCS) = make_float4(v0.x, v1.x, v2.x, v3.x);
            *reinterpret_cast<float4*>(dst + 1 * kCS) = make_float4(v0.y, v1.y, v2.y, v3.y);
            *reinterpret_cast<float4*>(dst + 2 * kCS) = make_float4(v0.z, v1.z, v2.z, v3.z);
            *reinterpret_cast<float4*>(dst + 3 * kCS) = make_float4(v0.w, v1.w, v2.w, v3.w);
        }
    }

    // ---------------- merged 3-tap tables (448 entries, one shot) ----------------
    if (tid < 2 * kNT) {
        const int e = tid;
        const int axis = (e >= kNT) ? 1 : 0;               // 0=y, 1=x
        const int idx  = axis ? e - kNT : e;
        const int r = idx / kPH;
        const int g = idx - r * kPH;
        const float lo = rois[r * 5 + (axis ? 1 : 2)] * kSCALE;
        const float hi = rois[r * 5 + (axis ? 3 : 4)] * kSCALE;
        const float sz   = fmaxf(hi - lo, 1.0f);
        const float bin  = sz * (1.0f / 7.0f);
        const float half = bin * 0.5f;
        const float c0r = lo + (float)g * bin + 0.5f * half;
        float wk0 = 0.f, wk1 = 0.f, wk2 = 0.f;
        int base = 0;
        #pragma unroll
        for (int sidx = 0; sidx < 2; ++sidx) {
            const float coord = c0r + (sidx ? half : 0.f);
            const bool valid = (coord >= -1.0f) && (coord <= 16.0f);
            const float c = fminf(fmaxf(coord, 0.0f), 15.0f);
            const int i0 = (int)floorf(c);
            const int i1 = (i0 + 1 < 16) ? i0 + 1 : 15;
            const float lf = c - (float)i0;
            const float w0 = valid ? (1.0f - lf) * 0.5f : 0.f;   // 0.5: folded mean
            const float w1 = valid ? lf * 0.5f : 0.f;
            if (sidx == 0) base = i0;
            const int d0 = i0 - base;                      // 0..1 (samples <1 cell apart)
            const int d1 = i1 - base;                      // 0..2
            wk0 += (d0 == 0) ? w0 : 0.f;
            wk1 += (d0 == 1) ? w0 : 0.f;
            wk0 += (d1 == 0) ? w1 : 0.f;
            wk1 += (d1 == 1) ? w1 : 0.f;
            wk2 += (d1 == 2) ? w1 : 0.f;
        }
        // clamp-shift: weights past index 15 are provably zero -> shift window
        const int sh = (base > 13) ? (base - 13) : 0;      // 0..2
        const float s0 = (sh == 0) ? wk0 : 0.f;
        const float s1 = (sh == 0) ? wk1 : ((sh == 1) ? wk0 : 0.f);
        const float s2 = (sh == 0) ? wk2 : ((sh == 1) ? wk1 : wk0);
        base -= sh;
        float4 tv;
        tv.x = s0; tv.y = s1; tv.z = s2;
        tv.w = __int_as_float(base * (axis ? kCS : kRS));
        if (axis) sxt[idx] = tv; else syt[idx] = tv;
    }
    if (tid == 0) {
        int n = 0;
        for (int r = 0; r < kNROI; ++r)
            if ((int)rois[r * 5] == b) slist[n++] = r;
        snroi = n;
    }
    __syncthreads();

    // ---------------- compute: group(16 lanes) = (roi, ph, quad) ----------------
    const int G = tid >> 4;                   // 0..31
    const int s16 = tid & 15;
    const int laneoff = s16 * 4;              // plane offset within cell column
    const int nit = snroi * 14;               // (roi, ph 0..6, quad 0..1)
    for (int item = G; item < nit; item += 32) {
        const int li   = item / 14;
        const int rest = item - li * 14;
        const int quad = (rest >= 7) ? 1 : 0;
        const int ph   = rest - quad * 7;
        const int r    = slist[li];
        const float4 ty = syt[r * kPH + ph];
        const int rowoff = __float_as_int(ty.w) + laneoff;

        float4 a0, a1, a2, a3;
        #define SUBBIN(ACC, K) { \
            const float4 tx = sxt[r * kPW + 3 * quad + (K)]; \
            const float* p = sp + rowoff + __float_as_int(tx.w); \
            const float wy[3] = {ty.x, ty.y, ty.z}; \
            const float wx[3] = {tx.x, tx.y, tx.z}; \
            float4 acc = make_float4(0.f, 0.f, 0.f, 0.f); \
            _Pragma("unroll") \
            for (int i = 0; i < 3; ++i) { \
                _Pragma("unroll") \
                for (int j = 0; j < 3; ++j) { \
                    const float wgt = wy[i] * wx[j]; \
                    const float4 v = *reinterpret_cast<const float4*>(p + i * kRS + j * kCS); \
                    acc.x += wgt * v.x; acc.y += wgt * v.y; \
                    acc.z += wgt * v.z; acc.w += wgt * v.w; \
                } \
            } \
            ACC = acc; }
        SUBBIN(a0, 0)
        SUBBIN(a1, 1)
        SUBBIN(a2, 2)
        SUBBIN(a3, 3)
        #undef SUBBIN

        // lane holds 4 planes (laneoff..+3) x 4 bins (pw = 3*quad..+3)
        float* dst = out + (size_t)(r * kCL + cl0 + laneoff) * 49 + ph * 7 + 3 * quad;
        dst[0] = a0.x; dst[1] = a1.x; dst[2] = a2.x; dst[3] = a3.x;
        dst += 49;
        dst[0] = a0.y; dst[1] = a1.y; dst[2] = a2.y; dst[3] = a3.y;
        dst += 49;
        dst[0] = a0.z; dst[1] = a1.z; dst[2] = a2.z; dst[3] = a3.z;
        dst += 49;
        dst[0] = a0.w; dst[1] = a1.w; dst[2] = a2.w; dst[3] = a3.w;
    }
}

extern "C" void kernel_launch(void* const* d_in, const int* in_sizes, int n_in,
                              void* d_out, int out_size, void* d_ws, size_t ws_size,
                              hipStream_t stream) {
    const float* input = (const float*)d_in[0];
    const float* rois  = (const float*)d_in[1];
    float* out = (float*)d_out;
    const int nblk = (kCL / kPPB) * 2;        // 512 plane-blocks x 2 batches
    roialign3d_kernel<<<dim3(nblk), dim3(kTPB), 0, stream>>>(input, rois, out);
}

// Round 4
// 55.158 us; speedup vs baseline: 14.6520x; 14.6520x over previous
//
#include <hip/hip_runtime.h>

// ROIAlign3d: input [2,1024,32,16,16] f32, rois [32,5] f32 -> out [32,1024,32,7,7] f32
//
// Round-4 design (round-1 skeleton, repaired):
//  - grid 2048 x 256: block owns 16 (c,l) planes, stages BOTH batches
//    (32 planes) into LDS transposed to [y][x][plane32].
//  - store mapping proven in R1 (202 MB written): thread <-> (roi,bin),
//    consecutive lanes write consecutive bins -> contiguous wave stores.
//    R3's 16-lane-group mapping caused 12x write amplification -- reverted.
//  - merged 3x3 tap stencil (R2/R3-proven): 9 taps/output instead of 16.
//    clamp-shift keeps all reads inside y,x in [0,15]: no zero-fill needed.
//  - bank-diagonal layout: cell stride 36 floats (9 granules == 1 mod 8),
//    row stride 580 floats (145 granules == 1 mod 8) -> tap bank-group
//    (y + x + pg) mod 8 rotates in BOTH axes; fixes R1's same-x ~14-way
//    collisions (bank-group there was x-only).

constexpr int kPH = 7, kPW = 7;
constexpr float kSCALE = 0.0625f;
constexpr int kNC = 1024, kNL = 32;
constexpr int kCL = kNC * kNL;            // 32768 planes per batch
constexpr int kNROI = 32;
constexpr int kPPB = 16;                  // (c,l) planes per block
constexpr int kTPB = 256;
constexpr int kCS = 36;                   // floats per cell (32 planes + 4 pad)
constexpr int kRS = 16 * kCS + 4;         // 580 floats per y-row (+1 granule)
constexpr int kSPN = 16 * kRS;            // 9280 floats = 37120 B
constexpr int kNT = kNROI * kPH;          // 224 table entries per axis
constexpr int kNBIN = kPH * kPW;          // 49

__global__ __launch_bounds__(kTPB) void roialign3d_kernel(
    const float* __restrict__ input, const float* __restrict__ rois,
    float* __restrict__ out)
{
    __shared__ __align__(16) float sp[kSPN];
    __shared__ __align__(16) float4 syt[kNT];   // w0,w1,w2, bitcast(ybase*kRS)
    __shared__ __align__(16) float4 sxt[kNT];   // w0,w1,w2, bitcast(xbase*kCS)
    __shared__ int sbofs[kNROI];                // batch offset in plane dim (0|16)

    const int cl0 = blockIdx.x * kPPB;
    const int tid = threadIdx.x;

    // ---- stage 2 batches x 16 planes, transposed to [y][x][plane] ----
    {
        const int pi = tid >> 3;               // 0..31 = b*16 + p
        const int bb = pi >> 4, p = pi & 15;
        const float4* src = reinterpret_cast<const float4*>(
            input + (size_t)(bb * kCL + cl0 + p) * 256);
        #pragma unroll
        for (int j = 0; j < 8; ++j) {
            const int f = (tid & 7) + j * 8;   // float4 index 0..63
            const float4 v = src[f];
            const int e = f * 4;
            const int y = e >> 4, x = e & 15;  // x in {0,4,8,12}; cells e..e+3 same row
            float* d = sp + y * kRS + x * kCS + pi;
            d[0 * kCS] = v.x;
            d[1 * kCS] = v.y;
            d[2 * kCS] = v.z;
            d[3 * kCS] = v.w;
        }
    }

    // ---- merged 3-tap tables: 448 entries ----
    for (int e = tid; e < 2 * kNT; e += kTPB) {
        const int axis = (e >= kNT) ? 1 : 0;   // 0=y, 1=x
        const int idx  = axis ? e - kNT : e;
        const int r = idx / kPH;
        const int g = idx - r * kPH;
        const float lo = rois[r * 5 + (axis ? 1 : 2)] * kSCALE;
        const float hi = rois[r * 5 + (axis ? 3 : 4)] * kSCALE;
        const float sz   = fmaxf(hi - lo, 1.0f);
        const float bin  = sz * (1.0f / 7.0f);
        const float half = bin * 0.5f;
        const float c0r  = lo + (float)g * bin + 0.5f * half;
        float wk0 = 0.f, wk1 = 0.f, wk2 = 0.f;
        int base = 0;
        #pragma unroll
        for (int sidx = 0; sidx < 2; ++sidx) {
            const float coord = c0r + (sidx ? half : 0.f);
            const bool valid = (coord >= -1.0f) && (coord <= 16.0f);
            const float c = fminf(fmaxf(coord, 0.0f), 15.0f);
            const int i0 = (int)floorf(c);
            const int i1 = (i0 + 1 < 16) ? i0 + 1 : 15;
            const float lf = c - (float)i0;
            const float w0 = valid ? (1.0f - lf) * 0.5f : 0.f;  // 0.5: folded 2x2 mean
            const float w1 = valid ? lf * 0.5f : 0.f;
            if (sidx == 0) base = i0;
            const int d0 = i0 - base;          // 0..1 (samples < 1 cell apart)
            const int d1 = i1 - base;          // 0..2
            wk0 += (d0 == 0) ? w0 : 0.f;
            wk1 += (d0 == 1) ? w0 : 0.f;
            wk0 += (d1 == 0) ? w1 : 0.f;
            wk1 += (d1 == 1) ? w1 : 0.f;
            wk2 += (d1 == 2) ? w1 : 0.f;
        }
        // clamp-shift: if base>13 the out-of-range weights are provably zero
        const int sh = (base > 13) ? (base - 13) : 0;          // 0..2
        const float s0 = (sh == 0) ? wk0 : 0.f;
        const float s1 = (sh == 0) ? wk1 : ((sh == 1) ? wk0 : 0.f);
        const float s2 = (sh == 0) ? wk2 : ((sh == 1) ? wk1 : wk0);
        base -= sh;
        float4 tv;
        tv.x = s0; tv.y = s1; tv.z = s2;
        tv.w = __int_as_float(base * (axis ? kCS : kRS));
        if (axis) sxt[idx] = tv; else syt[idx] = tv;
    }
    if (tid < kNROI) sbofs[tid] = ((int)rois[tid * 5]) << 4;
    __syncthreads();

    // ---- compute: thread <-> (roi, bin); 16 planes each ----
    for (int it = tid; it < kNROI * kNBIN; it += kTPB) {
        const int r   = it / kNBIN;
        const int bin = it - r * kNBIN;
        const int ph  = bin / kPW;
        const int pw  = bin - ph * kPW;

        const float4 ty = syt[r * kPH + ph];
        const float4 tx = sxt[r * kPW + pw];
        const int base = __float_as_int(ty.w) + __float_as_int(tx.w) + sbofs[r];

        const float wy[3] = {ty.x, ty.y, ty.z};
        const float wx[3] = {tx.x, tx.y, tx.z};

        float4 acc[4] = {};
        #pragma unroll
        for (int i = 0; i < 3; ++i) {
            #pragma unroll
            for (int j = 0; j < 3; ++j) {
                const float w = wy[i] * wx[j];
                const float* cp = sp + base + i * kRS + j * kCS;
                #pragma unroll
                for (int pg = 0; pg < 4; ++pg) {
                    const float4 v = *reinterpret_cast<const float4*>(cp + pg * 4);
                    acc[pg].x += w * v.x;
                    acc[pg].y += w * v.y;
                    acc[pg].z += w * v.z;
                    acc[pg].w += w * v.w;
                }
            }
        }

        float* dst = out + (size_t)(r * kCL + cl0) * kNBIN + bin;
        #pragma unroll
        for (int pg = 0; pg < 4; ++pg) {
            dst[(pg * 4 + 0) * kNBIN] = acc[pg].x;
            dst[(pg * 4 + 1) * kNBIN] = acc[pg].y;
            dst[(pg * 4 + 2) * kNBIN] = acc[pg].z;
            dst[(pg * 4 + 3) * kNBIN] = acc[pg].w;
        }
    }
}

extern "C" void kernel_launch(void* const* d_in, const int* in_sizes, int n_in,
                              void* d_out, int out_size, void* d_ws, size_t ws_size,
                              hipStream_t stream) {
    const float* input = (const float*)d_in[0];
    const float* rois  = (const float*)d_in[1];
    float* out = (float*)d_out;
    roialign3d_kernel<<<dim3(kCL / kPPB), dim3(kTPB), 0, stream>>>(input, rois, out);
}